// Round 17
// baseline (767.467 us; speedup 1.0000x reference)
//
#include <hip/hip_runtime.h>
#include <cstdint>
#include <cstddef>

typedef unsigned short u16;
typedef __attribute__((ext_vector_type(8))) short short8;
typedef __attribute__((ext_vector_type(4))) float f32x4;
typedef __attribute__((ext_vector_type(4))) unsigned short us4;

#define NB 2
#define SEQ 2048
#define DMODEL 512
#define DINNER 1024
#define NSTATE 16
#define RKK 32
#define NLAYER 4
#define VOCAB 32000
#define MROWS 4096      // NB*SEQ
#define NCHUNK 64
#define LCHUNK 32
#define XP_SPLITK 8
#define XP_KCH 128
#define OUT_SPLITK 4

#define GLOAD16(gp, lp) __builtin_amdgcn_global_load_lds( \
    (const __attribute__((address_space(1))) void*)(gp),  \
    (__attribute__((address_space(3))) void*)(lp), 16, 0, 0)

static __device__ __forceinline__ u16 f2bf(float f) {
  union { float f; uint32_t u; } v; v.f = f;
  uint32_t r = (v.u + 0x7FFFu + ((v.u >> 16) & 1u)) >> 16;
  return (u16)r;
}
static __device__ __forceinline__ float bf2f(u16 x) {
  union { uint32_t u; float f; } v; v.u = ((uint32_t)x) << 16; return v.f;
}

// ---------------- fused weight conversion (5 regions, vec4) ----------------
__global__ __launch_bounds__(256) void cvt_all_k(
    const float* __restrict__ ipw, const float* __restrict__ dtw,
    const float* __restrict__ opw, const float* __restrict__ dw,
    const float* __restrict__ xpw,
    u16* __restrict__ w_in, u16* __restrict__ w_dt,
    u16* __restrict__ w_out, u16* __restrict__ w_dec,
    u16* __restrict__ w_xp) {
  const long n0 = (long)NLAYER * 2 * DINNER * DMODEL / 4;
  const long n1 = (long)NLAYER * DINNER * RKK / 4;
  const long n2 = (long)NLAYER * DMODEL * DINNER / 4;
  const long n3 = (long)VOCAB * DMODEL / 4;
  const long n4 = (long)NLAYER * 128 * DINNER / 4;
  long i = (long)blockIdx.x * 256 + threadIdx.x;
  if (i >= n0 + n1 + n2 + n3 + n4) return;
  if (i >= n0 + n1 + n2 + n3) {
    long o4 = (i - n0 - n1 - n2 - n3) * 4;
    int c = (int)(o4 & 1023); int r = ((int)(o4 >> 10)) & 127; int l = (int)(o4 >> 17);
    us4 o;
    if (r < 64) {
      f32x4 v = *(const f32x4*)(xpw + (((long)l * 64 + r) << 10) + c);
      o.x = f2bf(v.x); o.y = f2bf(v.y); o.z = f2bf(v.z); o.w = f2bf(v.w);
    } else { o.x = 0; o.y = 0; o.z = 0; o.w = 0; }
    *(us4*)(w_xp + o4) = o;
    return;
  }
  const float* s; u16* d; long off;
  if (i < n0) { s = ipw; d = w_in; off = i; }
  else if (i < n0 + n1) { s = dtw; d = w_dt; off = i - n0; }
  else if (i < n0 + n1 + n2) { s = opw; d = w_out; off = i - n0 - n1; }
  else { s = dw; d = w_dec; off = i - n0 - n1 - n2; }
  f32x4 v = *(const f32x4*)(s + off * 4);
  us4 o; o.x = f2bf(v.x); o.y = f2bf(v.y); o.z = f2bf(v.z); o.w = f2bf(v.w);
  *(us4*)(d + off * 4) = o;
}

// ---------------- layernorm; MODE 0: embed-gather; MODE 1: + 4 bf16 partials;
// ---------------- MODE 2: same as 1 but no resid writeback (final LN) ----
template <int MODE>
__global__ __launch_bounds__(256) void ln_k(const int* __restrict__ ids, const float* __restrict__ emb,
                                            float* __restrict__ resid, const u16* __restrict__ hPb,
                                            long pstride,
                                            const float* __restrict__ w, const float* __restrict__ b,
                                            u16* __restrict__ obf) {
  int m = blockIdx.x, t = threadIdx.x;
  long base = (long)m * DMODEL;
  float x0, x1;
  if (MODE == 0) {
    long ebase = (long)ids[m] * DMODEL;
    x0 = emb[ebase + t]; x1 = emb[ebase + t + 256];
    resid[base + t] = x0; resid[base + t + 256] = x1;
  } else {
    x0 = resid[base + t];
    x1 = resid[base + t + 256];
    #pragma unroll
    for (int z = 0; z < OUT_SPLITK; ++z) {
      x0 += bf2f(hPb[z * pstride + base + t]);
      x1 += bf2f(hPb[z * pstride + base + t + 256]);
    }
    if (MODE == 1) {
      resid[base + t] = x0; resid[base + t + 256] = x1;
    }
  }
  float s = x0 + x1, q = x0 * x0 + x1 * x1;
  #pragma unroll
  for (int o = 1; o < 64; o <<= 1) { s += __shfl_xor(s, o, 64); q += __shfl_xor(q, o, 64); }
  __shared__ float ss[4], qq[4];
  int wv = t >> 6;
  if ((t & 63) == 0) { ss[wv] = s; qq[wv] = q; }
  __syncthreads();
  s = ss[0] + ss[1] + ss[2] + ss[3];
  q = qq[0] + qq[1] + qq[2] + qq[3];
  float mean = s * (1.f / DMODEL);
  float var = q * (1.f / DMODEL) - mean * mean;
  float rs = rsqrtf(var + 1e-5f);
  obf[base + t]       = f2bf((x0 - mean) * rs * w[t] + b[t]);
  obf[base + t + 256] = f2bf((x1 - mean) * rs * w[t + 256] + b[t + 256]);
}

// ---------------- depthwise causal conv1d + bias + silu (bf16 in/out, 8 t/thread) ------
__global__ __launch_bounds__(256) void conv_silu_k(const u16* __restrict__ xzb, const float* __restrict__ cw,
                            const float* __restrict__ cb, u16* __restrict__ ub) {
  int tid = blockIdx.x * 256 + threadIdx.x;
  int d = tid & (DINNER - 1);
  int g = tid >> 10;
  int m0 = g << 3;
  int t0 = m0 & (SEQ - 1);
  float w0 = cw[d * 4 + 0], w1 = cw[d * 4 + 1], w2 = cw[d * 4 + 2], w3 = cw[d * 4 + 3];
  float bias = cb[d];
  float v[11];
  #pragma unroll
  for (int j = 0; j < 11; ++j) {
    int tt = t0 + j - 3;
    v[j] = (tt >= 0) ? bf2f(xzb[(long)(m0 + j - 3) * (2 * DINNER) + d]) : 0.f;
  }
  #pragma unroll
  for (int i = 0; i < 8; ++i) {
    float acc = bias + v[i] * w0 + v[i + 1] * w1 + v[i + 2] * w2 + v[i + 3] * w3;
    float sv = acc / (1.f + __expf(-acc));
    ub[(long)(m0 + i) * DINNER + d] = f2bf(sv);
  }
}

// ---------------- GEMM: C[M,N] = A[M,K](bf16) * W[N,K](bf16)^T ----------------
// 128x128 tile, BK=32/64, 4 waves. BK=64 uses both-sides XOR bank swizzle.
// EPI: 0 = f32; 1 = bf16 only; 2 = softplus(v+bias) bf16; 3 = f32(v+bias) nontemporal
// NLIM: only write output cols < NLIM (xp split writes cols 0..63 only)
template <int EPI, int BK, bool SPLIT, int NLIM = (1 << 30)>
__global__ __launch_bounds__(256) void gemm_bf16(
    const u16* __restrict__ A, int lda, const u16* __restrict__ W, int ldw,
    float* __restrict__ C, u16* __restrict__ Cb, int ldc,
    const float* __restrict__ bias, int K, int kchunk, long zstride) {
  const int tid = threadIdx.x;
  const int nwg = gridDim.x * gridDim.y;
  const int wgid = blockIdx.y * gridDim.x + blockIdx.x;
  const int q = nwg >> 3;
  const int swz = (wgid & 7) * q + (wgid >> 3);
  const int bn = swz % gridDim.x, bm = swz / gridDim.x;
  int kb = 0, ke = K;
  if (SPLIT) {
    kb = blockIdx.z * kchunk; ke = kb + kchunk;
    C += (long)blockIdx.z * zstride;
    Cb += (long)blockIdx.z * zstride;
  }
  const int wave = tid >> 6, lane = tid & 63;
  const int wm = (wave >> 1) * 64, wn = (wave & 1) * 64;
  __shared__ __align__(16) u16 sA[128 * BK];
  __shared__ __align__(16) u16 sB[128 * BK];
  f32x4 acc[4][4] = {};
  const long arow0 = (long)bm * 128, brow0 = (long)bn * 128;
  const int frow = lane & 15, fk = (lane >> 4) << 3;
  const int rsw = (frow & 7) << 3;   // read-side swizzle (BK=64 only)
  for (int k0 = kb; k0 < ke; k0 += BK) {
    __syncthreads();
    if (BK == 32) {
      const int srow = lane >> 2, scol = (lane & 3) << 3;
      #pragma unroll
      for (int i = 0; i < 2; ++i) {
        int c = wave * 2 + i;
        GLOAD16(A + (arow0 + 16 * c + srow) * (long)lda + k0 + scol, sA + c * 512);
        GLOAD16(W + (brow0 + 16 * c + srow) * (long)ldw + k0 + scol, sB + c * 512);
      }
    } else {
      const int srow = lane >> 3;
      const int scol = (((lane & 7) ^ (lane >> 3)) << 3);
      #pragma unroll
      for (int i = 0; i < 4; ++i) {
        int c = wave * 4 + i;
        GLOAD16(A + (arow0 + 8 * c + srow) * (long)lda + k0 + scol, sA + c * 512);
        GLOAD16(W + (brow0 + 8 * c + srow) * (long)ldw + k0 + scol, sB + c * 512);
      }
    }
    asm volatile("s_waitcnt vmcnt(0)" ::: "memory");
    __syncthreads();
    #pragma unroll
    for (int ks = 0; ks < BK / 32; ++ks) {
      short8 aF[4], bF[4];
      #pragma unroll
      for (int i = 0; i < 4; ++i) {
        int idx = (wm + i * 16 + frow) * BK + ks * 32 + fk;
        aF[i] = *(const short8*)(sA + (BK == 64 ? (idx ^ rsw) : idx));
      }
      #pragma unroll
      for (int i = 0; i < 4; ++i) {
        int idx = (wn + i * 16 + frow) * BK + ks * 32 + fk;
        bF[i] = *(const short8*)(sB + (BK == 64 ? (idx ^ rsw) : idx));
      }
      #pragma unroll
      for (int mi = 0; mi < 4; ++mi)
        #pragma unroll
        for (int ni = 0; ni < 4; ++ni)
          acc[mi][ni] = __builtin_amdgcn_mfma_f32_16x16x32_bf16(aF[mi], bF[ni], acc[mi][ni], 0, 0, 0);
    }
  }
  const int ccol = lane & 15, crow = (lane >> 4) << 2;
  #pragma unroll
  for (int mi = 0; mi < 4; ++mi) {
    #pragma unroll
    for (int ni = 0; ni < 4; ++ni) {
      long gr0 = arow0 + wm + mi * 16 + crow;
      long gc = brow0 + wn + ni * 16 + ccol;
      if (brow0 + wn + ni * 16 >= NLIM) continue;   // unused cols (zero-pad region)
      #pragma unroll
      for (int r = 0; r < 4; ++r) {
        float v = acc[mi][ni][r];
        long idx = (gr0 + r) * (long)ldc + gc;
        if (EPI == 0) {
          C[idx] = v;
        } else if (EPI == 1) {
          Cb[idx] = f2bf(v);
        } else if (EPI == 2) {
          float x = v + bias[gc];
          Cb[idx] = f2bf((x > 20.f) ? x : log1pf(__expf(x)));
        } else {
          __builtin_nontemporal_store(v + bias[gc], &C[idx]);
        }
      }
    }
  }
}

// ---------------- decode GEMM: 256x128 tile, 8 waves, BK=32, 2-phase dbuf ----------------
__global__ __launch_bounds__(512) void gemm_dec(
    const u16* __restrict__ A, const u16* __restrict__ W,
    float* __restrict__ C, const float* __restrict__ bias) {
  const int tid = threadIdx.x;
  const int nwg = gridDim.x * gridDim.y;      // 250*16 = 4000
  const int wgid = blockIdx.y * gridDim.x + blockIdx.x;
  const int q = nwg >> 3;
  const int swz = (wgid & 7) * q + (wgid >> 3);
  const int bn = swz % gridDim.x, bm = swz / gridDim.x;
  const int wave = tid >> 6, lane = tid & 63;
  const int wm = (wave >> 1) << 6;            // 0,64,128,192
  const int wn = (wave & 1) << 6;             // 0,64
  __shared__ __align__(16) u16 sA[2][256 * 32];  // 2 x 16 KB
  __shared__ __align__(16) u16 sB[2][128 * 32];  // 2 x 8 KB
  f32x4 acc[4][4] = {};
  const long arow0 = (long)bm * 256, brow0 = (long)bn * 128;
  const int frow = lane & 15, fk = (lane >> 4) << 3;
  const int srow = lane >> 2;
  const int scol = (((lane & 3) ^ (srow & 3)) << 3);
  #pragma unroll
  for (int i = 0; i < 2; ++i) {
    int c = wave * 2 + i;
    GLOAD16(A + (arow0 + 16 * c + srow) * (long)DMODEL + scol, sA[0] + c * 512);
  }
  GLOAD16(W + (brow0 + 16 * wave + srow) * (long)DMODEL + scol, sB[0] + wave * 512);
  asm volatile("s_waitcnt vmcnt(0)" ::: "memory");
  __syncthreads();
  int cur = 0;
  for (int k0 = 0; k0 < DMODEL; k0 += 32) {
    if (k0 + 32 < DMODEL) {
      int nb = cur ^ 1;
      #pragma unroll
      for (int i = 0; i < 2; ++i) {
        int c = wave * 2 + i;
        GLOAD16(A + (arow0 + 16 * c + srow) * (long)DMODEL + k0 + 32 + scol, sA[nb] + c * 512);
      }
      GLOAD16(W + (brow0 + 16 * wave + srow) * (long)DMODEL + k0 + 32 + scol, sB[nb] + wave * 512);
    }
    short8 aF[4], bF[4];
    #pragma unroll
    for (int i = 0; i < 4; ++i) {
      int row = wm + i * 16 + frow;
      aF[i] = *(const short8*)(sA[cur] + ((row * 32 + fk) ^ ((row & 3) << 3)));
    }
    #pragma unroll
    for (int i = 0; i < 4; ++i) {
      int row = wn + i * 16 + frow;
      bF[i] = *(const short8*)(sB[cur] + ((row * 32 + fk) ^ ((row & 3) << 3)));
    }
    #pragma unroll
    for (int mi = 0; mi < 4; ++mi)
      #pragma unroll
      for (int ni = 0; ni < 4; ++ni)
        acc[mi][ni] = __builtin_amdgcn_mfma_f32_16x16x32_bf16(aF[mi], bF[ni], acc[mi][ni], 0, 0, 0);
    asm volatile("s_waitcnt vmcnt(0)" ::: "memory");
    __syncthreads();
    cur ^= 1;
  }
  const int ccol = lane & 15, crow = (lane >> 4) << 2;
  #pragma unroll
  for (int mi = 0; mi < 4; ++mi) {
    #pragma unroll
    for (int ni = 0; ni < 4; ++ni) {
      long gr0 = arow0 + wm + mi * 16 + crow;
      long gc = brow0 + wn + ni * 16 + ccol;
      float bv = bias[gc];
      #pragma unroll
      for (int r = 0; r < 4; ++r)
        __builtin_nontemporal_store(acc[mi][ni][r] + bv, &C[(gr0 + r) * (long)VOCAB + gc]);
    }
  }
}

// ---------------- fused xp-combine + dt projection ----------------
// block = 16 rows. Sum 8 partials (cols 0..63) -> LDS; write f32 B/C cols 32..63;
// dt[row][d] = softplus(sum[row][0:32] . wdt[d] + bias[d]) -> bf16. 4 d per thread.
__global__ __launch_bounds__(256) void xpdt_k(
    const float* __restrict__ P, const u16* __restrict__ wdt,
    const float* __restrict__ bias, float* __restrict__ xd,
    u16* __restrict__ dtb16) {
  const int tid = threadIdx.x;
  const int row0 = blockIdx.x * 16;   // 256 blocks
  __shared__ float sS[16][64];
  #pragma unroll
  for (int it = 0; it < 4; ++it) {
    int idx = it * 256 + tid;         // 0..1023
    int r = idx >> 6, col = idx & 63;
    long o = (long)(row0 + r) * 128 + col;
    float s = 0.f;
    #pragma unroll
    for (int z = 0; z < XP_SPLITK; ++z) s += P[(long)z * MROWS * 128 + o];
    sS[r][col] = s;
    if (col >= 32) xd[o] = s;
  }
  short8 w[4][4];
  float bv[4];
  #pragma unroll
  for (int j = 0; j < 4; ++j) {
    int d = tid + j * 256;
    #pragma unroll
    for (int k = 0; k < 4; ++k) w[j][k] = *(const short8*)(wdt + d * RKK + k * 8);
    bv[j] = bias[d];
  }
  __syncthreads();
  for (int r = 0; r < 16; ++r) {
    float sv[32];
    #pragma unroll
    for (int k = 0; k < 32; ++k) sv[k] = sS[r][k];
    #pragma unroll
    for (int j = 0; j < 4; ++j) {
      float acc = bv[j];
      #pragma unroll
      for (int k = 0; k < 4; ++k)
        #pragma unroll
        for (int e = 0; e < 8; ++e)
          acc += sv[k * 8 + e] * bf2f((u16)w[j][k][e]);
      float dt = (acc > 20.f) ? acc : log1pf(__expf(acc));
      dtb16[(long)(row0 + r) * DINNER + tid + j * 256] = f2bf(dt);
    }
  }
}

// ---------------- chunked selective scan (3-kernel path, NCHUNK=64) ----------------
__global__ __launch_bounds__(256) void scanA_k(const u16* __restrict__ dtb, const u16* __restrict__ ubf,
                        const float* __restrict__ xd, const float* __restrict__ alog_l,
                        float* __restrict__ P, float* __restrict__ S) {
  int bid = blockIdx.x;   // NB*NCHUNK*4 = 512
  int tid = threadIdx.x;
  int b = bid >> 8;
  int c = (bid >> 2) & (NCHUNK - 1);
  int d = ((bid & 3) << 8) + tid;
  long rbase = (long)(b * SEQ + c * LCHUNK);
  __shared__ __align__(16) float sB[LCHUNK][NSTATE];
  if (tid < 128) {
    int t = tid >> 2, k4 = (tid & 3) << 2;
    *(f32x4*)&sB[t][k4] = *(const f32x4*)(xd + (rbase + t) * 128 + RKK + k4);
  }
  u16 dtv[LCHUNK], uv[LCHUNK];
  const u16* dp = dtb + rbase * DINNER + d;
  const u16* up = ubf + rbase * DINNER + d;
  #pragma unroll
  for (int tt = 0; tt < LCHUNK; ++tt) { dtv[tt] = dp[(long)tt * DINNER]; uv[tt] = up[(long)tt * DINNER]; }
  float A[NSTATE], h[NSTATE];
  #pragma unroll
  for (int n4 = 0; n4 < 4; ++n4) {
    f32x4 a4 = *(const f32x4*)(alog_l + d * NSTATE + n4 * 4);
    #pragma unroll
    for (int j = 0; j < 4; ++j) { A[n4 * 4 + j] = -__expf(a4[j]); h[n4 * 4 + j] = 0.f; }
  }
  __syncthreads();
  float dsum = 0.f;
  #pragma unroll
  for (int tt = 0; tt < LCHUNK; ++tt) {
    float dv = bf2f(dtv[tt]);
    float du = dv * bf2f(uv[tt]);
    dsum += dv;
    f32x4 b0 = *(const f32x4*)&sB[tt][0], b1 = *(const f32x4*)&sB[tt][4];
    f32x4 b2 = *(const f32x4*)&sB[tt][8], b3 = *(const f32x4*)&sB[tt][12];
    #pragma unroll
    for (int n = 0; n < NSTATE; ++n) {
      float dA = __expf(dv * A[n]);
      float bx = (n < 4) ? b0[n & 3] : (n < 8) ? b1[n & 3] : (n < 12) ? b2[n & 3] : b3[n & 3];
      h[n] = dA * h[n] + du * bx;
    }
  }
  long base = (((long)(b * DINNER + d)) * NCHUNK + c) * NSTATE;
  #pragma unroll
  for (int n4 = 0; n4 < 4; ++n4) {
    f32x4 pv, sv;
    #pragma unroll
    for (int j = 0; j < 4; ++j) { pv[j] = __expf(A[n4 * 4 + j] * dsum); sv[j] = h[n4 * 4 + j]; }
    *(f32x4*)(P + base + n4 * 4) = pv;
    *(f32x4*)(S + base + n4 * 4) = sv;
  }
}

// phase B: wave-parallel Kogge-Stone scan over chunks. wave = one (b,d); lane = chunk.
__global__ __launch_bounds__(256) void scanB_k(const float* __restrict__ P, const float* __restrict__ S,
                        float* __restrict__ Hin) {
  int w = blockIdx.x * 4 + (threadIdx.x >> 6);  // (b*DINNER + d), 2048 waves
  int lane = threadIdx.x & 63;
  long base = ((long)w * NCHUNK + lane) * NSTATE;
  float p[NSTATE], s[NSTATE];
  #pragma unroll
  for (int n = 0; n < NSTATE; ++n) { p[n] = P[base + n]; s[n] = S[base + n]; }
  #pragma unroll
  for (int off = 1; off < 64; off <<= 1) {
    float pp[NSTATE], sp[NSTATE];
    #pragma unroll
    for (int n = 0; n < NSTATE; ++n) {
      pp[n] = __shfl_up(p[n], off, 64);
      sp[n] = __shfl_up(s[n], off, 64);
    }
    if (lane >= off) {
      #pragma unroll
      for (int n = 0; n < NSTATE; ++n) { s[n] = p[n] * sp[n] + s[n]; p[n] *= pp[n]; }
    }
  }
  #pragma unroll
  for (int n = 0; n < NSTATE; ++n) {
    float hv = __shfl_up(s[n], 1, 64);
    Hin[base + n] = (lane == 0) ? 0.f : hv;
  }
}

// phase C: recompute within chunk with true h_in; y = (h.C + u*D) * silu(z) -> bf16
__global__ __launch_bounds__(256) void scanC_k(const u16* __restrict__ dtb, const u16* __restrict__ ubf,
                        const float* __restrict__ xd, const float* __restrict__ alog_l,
                        const float* __restrict__ Dp_l, const u16* __restrict__ xzb,
                        const float* __restrict__ Hin, u16* __restrict__ ybf) {
  int bid = blockIdx.x;
  int tid = threadIdx.x;
  int b = bid >> 8;
  int c = (bid >> 2) & (NCHUNK - 1);
  int d = ((bid & 3) << 8) + tid;
  long rbase = (long)(b * SEQ + c * LCHUNK);
  __shared__ __align__(16) float sBC[LCHUNK][2 * NSTATE];
  {
    int t = tid >> 3, k4 = (tid & 7) << 2;
    *(f32x4*)&sBC[t][k4] = *(const f32x4*)(xd + (rbase + t) * 128 + RKK + k4);
  }
  u16 dtv[LCHUNK], uv[LCHUNK], zv[LCHUNK];
  const u16* dp = dtb + rbase * DINNER + d;
  const u16* up = ubf + rbase * DINNER + d;
  const u16* zp = xzb + rbase * (2 * DINNER) + DINNER + d;
  #pragma unroll
  for (int tt = 0; tt < LCHUNK; ++tt) {
    dtv[tt] = dp[(long)tt * DINNER]; uv[tt] = up[(long)tt * DINNER];
    zv[tt] = zp[(long)tt * 2 * DINNER];
  }
  float A[NSTATE], h[NSTATE];
  long hbase = (((long)(b * DINNER + d)) * NCHUNK + c) * NSTATE;
  #pragma unroll
  for (int n4 = 0; n4 < 4; ++n4) {
    f32x4 a4 = *(const f32x4*)(alog_l + d * NSTATE + n4 * 4);
    f32x4 h4 = *(const f32x4*)(Hin + hbase + n4 * 4);
    #pragma unroll
    for (int j = 0; j < 4; ++j) { A[n4 * 4 + j] = -__expf(a4[j]); h[n4 * 4 + j] = h4[j]; }
  }
  float Dv = Dp_l[d];
  u16* yp = ybf + rbase * DINNER + d;
  __syncthreads();
  #pragma unroll
  for (int tt = 0; tt < LCHUNK; ++tt) {
    float dv = bf2f(dtv[tt]);
    float uvf = bf2f(uv[tt]);
    float du = dv * uvf;
    f32x4 b0 = *(const f32x4*)&sBC[tt][0], b1 = *(const f32x4*)&sBC[tt][4];
    f32x4 b2 = *(const f32x4*)&sBC[tt][8], b3 = *(const f32x4*)&sBC[tt][12];
    f32x4 c0 = *(const f32x4*)&sBC[tt][16], c1 = *(const f32x4*)&sBC[tt][20];
    f32x4 c2 = *(const f32x4*)&sBC[tt][24], c3 = *(const f32x4*)&sBC[tt][28];
    float y = 0.f;
    #pragma unroll
    for (int n = 0; n < NSTATE; ++n) {
      float dA = __expf(dv * A[n]);
      float bx = (n < 4) ? b0[n & 3] : (n < 8) ? b1[n & 3] : (n < 12) ? b2[n & 3] : b3[n & 3];
      float cx = (n < 4) ? c0[n & 3] : (n < 8) ? c1[n & 3] : (n < 12) ? c2[n & 3] : c3[n & 3];
      h[n] = dA * h[n] + du * bx;
      y += h[n] * cx;
    }
    y += uvf * Dv;
    float z = bf2f(zv[tt]);
    y *= z / (1.f + __expf(-z));
    yp[(long)tt * DINNER] = f2bf(y);
  }
}

// ---------------- launch ----------------
extern "C" void kernel_launch(void* const* d_in, const int* in_sizes, int n_in,
                              void* d_out, int out_size, void* d_ws, size_t ws_size,
                              hipStream_t stream) {
  (void)in_sizes; (void)n_in; (void)out_size; (void)ws_size;
  const int*   ids = (const int*)d_in[0];
  const float* emb = (const float*)d_in[1];
  const float* ipw = (const float*)d_in[2];
  const float* cw  = (const float*)d_in[3];
  const float* cb  = (const float*)d_in[4];
  const float* xpw = (const float*)d_in[5];
  const float* dtw = (const float*)d_in[6];
  const float* dtb = (const float*)d_in[7];
  const float* alg = (const float*)d_in[8];
  const float* Dpp = (const float*)d_in[9];
  const float* opw = (const float*)d_in[10];
  const float* nw  = (const float*)d_in[11];
  const float* nb  = (const float*)d_in[12];
  const float* nfw = (const float*)d_in[13];
  const float* nfb = (const float*)d_in[14];
  const float* dw  = (const float*)d_in[15];
  const float* db  = (const float*)d_in[16];

  char* p = (char*)d_ws;
  auto carve = [&](size_t bytes) { void* r = (void*)p; p += (bytes + 255) & ~(size_t)255; return r; };
  float* resid  = (float*)carve((size_t)MROWS * DMODEL * 4);
  u16*   hmixPb = (u16*)  carve((size_t)OUT_SPLITK * MROWS * DMODEL * 2);
  u16*   hnbf   = (u16*)  carve((size_t)MROWS * DMODEL * 2);
  u16*   hfbf   = (u16*)  carve((size_t)MROWS * DMODEL * 2);
  u16*   xzb    = (u16*)  carve((size_t)MROWS * 2 * DINNER * 2);
  u16*   ubf    = (u16*)  carve((size_t)MROWS * DINNER * 2);
  float* xdbl   = (float*)carve((size_t)MROWS * 128 * 4);
  float* xdP    = (float*)carve((size_t)XP_SPLITK * MROWS * 128 * 4);
  u16*   dtb16  = (u16*)  carve((size_t)MROWS * DINNER * 2);
  u16*   ybf    = (u16*)  carve((size_t)MROWS * DINNER * 2);
  float* chkP   = (float*)carve((size_t)NB * DINNER * NCHUNK * NSTATE * 4);
  float* chkS   = (float*)carve((size_t)NB * DINNER * NCHUNK * NSTATE * 4);
  float* hin    = (float*)carve((size_t)NB * DINNER * NCHUNK * NSTATE * 4);
  u16*   w_in   = (u16*)carve((size_t)NLAYER * 2 * DINNER * DMODEL * 2);
  u16*   w_xp   = (u16*)carve((size_t)NLAYER * 128 * DINNER * 2);
  u16*   w_dt   = (u16*)carve((size_t)NLAYER * DINNER * RKK * 2);
  u16*   w_out  = (u16*)carve((size_t)NLAYER * DMODEL * DINNER * 2);
  u16*   w_dec  = (u16*)carve((size_t)VOCAB * DMODEL * 2);

  { // weight conversions: single fused kernel (incl. padded xproj)
    long nv = ((long)NLAYER * 2 * DINNER * DMODEL + (long)NLAYER * DINNER * RKK +
               (long)NLAYER * DMODEL * DINNER + (long)VOCAB * DMODEL +
               (long)NLAYER * 128 * DINNER) / 4;
    cvt_all_k<<<(int)((nv + 255) / 256), 256, 0, stream>>>(
        ipw, dtw, opw, dw, xpw, w_in, w_dt, w_out, w_dec, w_xp);
  }

  for (int i = 0; i < NLAYER; ++i) {
    if (i == 0)
      ln_k<0><<<MROWS, 256, 0, stream>>>(ids, emb, resid, nullptr, 0, nw, nb, hnbf);
    else
      ln_k<1><<<MROWS, 256, 0, stream>>>(nullptr, nullptr, resid, hmixPb, (long)MROWS * DMODEL,
                                         nw + i * DMODEL, nb + i * DMODEL, hnbf);
    // xz = hn @ in_proj^T   [4096,2048] bf16
    gemm_bf16<1, 64, false><<<dim3(2 * DINNER / 128, MROWS / 128), 256, 0, stream>>>(
        hnbf, DMODEL, w_in + (long)i * 2 * DINNER * DMODEL, DMODEL,
        nullptr, xzb, 2 * DINNER, nullptr, DMODEL, 0, 0);
    conv_silu_k<<<(MROWS / 8 * DINNER) / 256, 256, 0, stream>>>(
        xzb, cw + (long)i * DINNER * 4, cb + i * DINNER, ubf);
    // xdbl = u @ x_proj^T (padded to 128 cols), split-K=8, write cols<64 only
    gemm_bf16<0, 64, true, 64><<<dim3(1, MROWS / 128, XP_SPLITK), 256, 0, stream>>>(
        ubf, DINNER, w_xp + (long)i * 128 * DINNER, DINNER,
        xdP, nullptr, 128, nullptr, DINNER, XP_KCH, (long)MROWS * 128);
    // fused: sum partials -> xdbl f32 (cols 32..63) + dt = softplus(.) -> bf16
    xpdt_k<<<MROWS / 16, 256, 0, stream>>>(
        xdP, w_dt + (long)i * DINNER * RKK, dtb + i * DINNER, xdbl, dtb16);
    scanA_k<<<NB * NCHUNK * 4, 256, 0, stream>>>(
        dtb16, ubf, xdbl, alg + (long)i * DINNER * NSTATE, chkP, chkS);
    scanB_k<<<(NB * DINNER) / 4, 256, 0, stream>>>(chkP, chkS, hin);
    scanC_k<<<NB * NCHUNK * 4, 256, 0, stream>>>(
        dtb16, ubf, xdbl, alg + (long)i * DINNER * NSTATE, Dpp + i * DINNER, xzb, hin, ybf);
    // hmix = y @ out_proj^T  [4096,512], split-K=4, bf16 partials (summed in next LN)
    gemm_bf16<1, 64, true><<<dim3(DMODEL / 128, MROWS / 128, OUT_SPLITK), 256, 0, stream>>>(
        ybf, DINNER, w_out + (long)i * DMODEL * DINNER, DINNER,
        nullptr, hmixPb, DMODEL, nullptr, DINNER, DINNER / OUT_SPLITK, (long)MROWS * DMODEL);
  }
  ln_k<2><<<MROWS, 256, 0, stream>>>(nullptr, nullptr, resid, hmixPb, (long)MROWS * DMODEL,
                                     nfw, nfb, hfbf);
  // logits = hf @ dec_w^T + dec_b  -> f32 out (256x128 tile, 8 waves, 2-phase, NT)
  gemm_dec<<<dim3(VOCAB / 128, MROWS / 256), 512, 0, stream>>>(
      hfbf, w_dec, (float*)d_out, db);
}

// Round 18
// 759.445 us; speedup vs baseline: 1.0106x; 1.0106x over previous
//
#include <hip/hip_runtime.h>
#include <cstdint>
#include <cstddef>

typedef unsigned short u16;
typedef __attribute__((ext_vector_type(8))) short short8;
typedef __attribute__((ext_vector_type(4))) float f32x4;
typedef __attribute__((ext_vector_type(4))) unsigned short us4;

#define NB 2
#define SEQ 2048
#define DMODEL 512
#define DINNER 1024
#define NSTATE 16
#define RKK 32
#define NLAYER 4
#define VOCAB 32000
#define MROWS 4096      // NB*SEQ
#define NCHUNK 64
#define LCHUNK 32
#define XP_SPLITK 8
#define XP_KCH 128
#define OUT_SPLITK 4

#define GLOAD16(gp, lp) __builtin_amdgcn_global_load_lds( \
    (const __attribute__((address_space(1))) void*)(gp),  \
    (__attribute__((address_space(3))) void*)(lp), 16, 0, 0)

static __device__ __forceinline__ u16 f2bf(float f) {
  union { float f; uint32_t u; } v; v.f = f;
  uint32_t r = (v.u + 0x7FFFu + ((v.u >> 16) & 1u)) >> 16;
  return (u16)r;
}
static __device__ __forceinline__ float bf2f(u16 x) {
  union { uint32_t u; float f; } v; v.u = ((uint32_t)x) << 16; return v.f;
}

// ---------------- fused weight conversion (5 regions, vec4) ----------------
__global__ __launch_bounds__(256) void cvt_all_k(
    const float* __restrict__ ipw, const float* __restrict__ dtw,
    const float* __restrict__ opw, const float* __restrict__ dw,
    const float* __restrict__ xpw,
    u16* __restrict__ w_in, u16* __restrict__ w_dt,
    u16* __restrict__ w_out, u16* __restrict__ w_dec,
    u16* __restrict__ w_xp) {
  const long n0 = (long)NLAYER * 2 * DINNER * DMODEL / 4;
  const long n1 = (long)NLAYER * DINNER * RKK / 4;
  const long n2 = (long)NLAYER * DMODEL * DINNER / 4;
  const long n3 = (long)VOCAB * DMODEL / 4;
  const long n4 = (long)NLAYER * 128 * DINNER / 4;
  long i = (long)blockIdx.x * 256 + threadIdx.x;
  if (i >= n0 + n1 + n2 + n3 + n4) return;
  if (i >= n0 + n1 + n2 + n3) {
    long o4 = (i - n0 - n1 - n2 - n3) * 4;
    int c = (int)(o4 & 1023); int r = ((int)(o4 >> 10)) & 127; int l = (int)(o4 >> 17);
    us4 o;
    if (r < 64) {
      f32x4 v = *(const f32x4*)(xpw + (((long)l * 64 + r) << 10) + c);
      o.x = f2bf(v.x); o.y = f2bf(v.y); o.z = f2bf(v.z); o.w = f2bf(v.w);
    } else { o.x = 0; o.y = 0; o.z = 0; o.w = 0; }
    *(us4*)(w_xp + o4) = o;
    return;
  }
  const float* s; u16* d; long off;
  if (i < n0) { s = ipw; d = w_in; off = i; }
  else if (i < n0 + n1) { s = dtw; d = w_dt; off = i - n0; }
  else if (i < n0 + n1 + n2) { s = opw; d = w_out; off = i - n0 - n1; }
  else { s = dw; d = w_dec; off = i - n0 - n1 - n2; }
  f32x4 v = *(const f32x4*)(s + off * 4);
  us4 o; o.x = f2bf(v.x); o.y = f2bf(v.y); o.z = f2bf(v.z); o.w = f2bf(v.w);
  *(us4*)(d + off * 4) = o;
}

// ---------------- layernorm; MODE 0: embed-gather; MODE 1: + 4 bf16 partials;
// ---------------- MODE 2: same as 1 but no resid writeback (final LN) ----
template <int MODE>
__global__ __launch_bounds__(256) void ln_k(const int* __restrict__ ids, const float* __restrict__ emb,
                                            float* __restrict__ resid, const u16* __restrict__ hPb,
                                            long pstride,
                                            const float* __restrict__ w, const float* __restrict__ b,
                                            u16* __restrict__ obf) {
  int m = blockIdx.x, t = threadIdx.x;
  long base = (long)m * DMODEL;
  float x0, x1;
  if (MODE == 0) {
    long ebase = (long)ids[m] * DMODEL;
    x0 = emb[ebase + t]; x1 = emb[ebase + t + 256];
    resid[base + t] = x0; resid[base + t + 256] = x1;
  } else {
    x0 = resid[base + t];
    x1 = resid[base + t + 256];
    #pragma unroll
    for (int z = 0; z < OUT_SPLITK; ++z) {
      x0 += bf2f(hPb[z * pstride + base + t]);
      x1 += bf2f(hPb[z * pstride + base + t + 256]);
    }
    if (MODE == 1) {
      resid[base + t] = x0; resid[base + t + 256] = x1;
    }
  }
  float s = x0 + x1, q = x0 * x0 + x1 * x1;
  #pragma unroll
  for (int o = 1; o < 64; o <<= 1) { s += __shfl_xor(s, o, 64); q += __shfl_xor(q, o, 64); }
  __shared__ float ss[4], qq[4];
  int wv = t >> 6;
  if ((t & 63) == 0) { ss[wv] = s; qq[wv] = q; }
  __syncthreads();
  s = ss[0] + ss[1] + ss[2] + ss[3];
  q = qq[0] + qq[1] + qq[2] + qq[3];
  float mean = s * (1.f / DMODEL);
  float var = q * (1.f / DMODEL) - mean * mean;
  float rs = rsqrtf(var + 1e-5f);
  obf[base + t]       = f2bf((x0 - mean) * rs * w[t] + b[t]);
  obf[base + t + 256] = f2bf((x1 - mean) * rs * w[t + 256] + b[t + 256]);
}

// ---------------- depthwise causal conv1d + bias + silu (bf16 in/out, 8 t/thread) ------
__global__ __launch_bounds__(256) void conv_silu_k(const u16* __restrict__ xzb, const float* __restrict__ cw,
                            const float* __restrict__ cb, u16* __restrict__ ub) {
  int tid = blockIdx.x * 256 + threadIdx.x;
  int d = tid & (DINNER - 1);
  int g = tid >> 10;
  int m0 = g << 3;
  int t0 = m0 & (SEQ - 1);
  float w0 = cw[d * 4 + 0], w1 = cw[d * 4 + 1], w2 = cw[d * 4 + 2], w3 = cw[d * 4 + 3];
  float bias = cb[d];
  float v[11];
  #pragma unroll
  for (int j = 0; j < 11; ++j) {
    int tt = t0 + j - 3;
    v[j] = (tt >= 0) ? bf2f(xzb[(long)(m0 + j - 3) * (2 * DINNER) + d]) : 0.f;
  }
  #pragma unroll
  for (int i = 0; i < 8; ++i) {
    float acc = bias + v[i] * w0 + v[i + 1] * w1 + v[i + 2] * w2 + v[i + 3] * w3;
    float sv = acc / (1.f + __expf(-acc));
    ub[(long)(m0 + i) * DINNER + d] = f2bf(sv);
  }
}

// ---------------- GEMM: C[M,N] = A[M,K](bf16) * W[N,K](bf16)^T ----------------
// 128x128 tile, BK=32/64, 4 waves. BK=64 uses both-sides XOR bank swizzle.
// EPI: 0 = f32; 1 = bf16 only; 2 = softplus(v+bias) bf16; 3 = f32(v+bias) nontemporal
// NLIM: only write output cols < NLIM (xp split writes cols 0..63 only)
template <int EPI, int BK, bool SPLIT, int NLIM = (1 << 30)>
__global__ __launch_bounds__(256) void gemm_bf16(
    const u16* __restrict__ A, int lda, const u16* __restrict__ W, int ldw,
    float* __restrict__ C, u16* __restrict__ Cb, int ldc,
    const float* __restrict__ bias, int K, int kchunk, long zstride) {
  const int tid = threadIdx.x;
  const int nwg = gridDim.x * gridDim.y;
  const int wgid = blockIdx.y * gridDim.x + blockIdx.x;
  const int q = nwg >> 3;
  const int swz = (wgid & 7) * q + (wgid >> 3);
  const int bn = swz % gridDim.x, bm = swz / gridDim.x;
  int kb = 0, ke = K;
  if (SPLIT) {
    kb = blockIdx.z * kchunk; ke = kb + kchunk;
    C += (long)blockIdx.z * zstride;
    Cb += (long)blockIdx.z * zstride;
  }
  const int wave = tid >> 6, lane = tid & 63;
  const int wm = (wave >> 1) * 64, wn = (wave & 1) * 64;
  __shared__ __align__(16) u16 sA[128 * BK];
  __shared__ __align__(16) u16 sB[128 * BK];
  f32x4 acc[4][4] = {};
  const long arow0 = (long)bm * 128, brow0 = (long)bn * 128;
  const int frow = lane & 15, fk = (lane >> 4) << 3;
  const int rsw = (frow & 7) << 3;   // read-side swizzle (BK=64 only)
  for (int k0 = kb; k0 < ke; k0 += BK) {
    __syncthreads();
    if (BK == 32) {
      const int srow = lane >> 2, scol = (lane & 3) << 3;
      #pragma unroll
      for (int i = 0; i < 2; ++i) {
        int c = wave * 2 + i;
        GLOAD16(A + (arow0 + 16 * c + srow) * (long)lda + k0 + scol, sA + c * 512);
        GLOAD16(W + (brow0 + 16 * c + srow) * (long)ldw + k0 + scol, sB + c * 512);
      }
    } else {
      const int srow = lane >> 3;
      const int scol = (((lane & 7) ^ (lane >> 3)) << 3);
      #pragma unroll
      for (int i = 0; i < 4; ++i) {
        int c = wave * 4 + i;
        GLOAD16(A + (arow0 + 8 * c + srow) * (long)lda + k0 + scol, sA + c * 512);
        GLOAD16(W + (brow0 + 8 * c + srow) * (long)ldw + k0 + scol, sB + c * 512);
      }
    }
    asm volatile("s_waitcnt vmcnt(0)" ::: "memory");
    __syncthreads();
    #pragma unroll
    for (int ks = 0; ks < BK / 32; ++ks) {
      short8 aF[4], bF[4];
      #pragma unroll
      for (int i = 0; i < 4; ++i) {
        int idx = (wm + i * 16 + frow) * BK + ks * 32 + fk;
        aF[i] = *(const short8*)(sA + (BK == 64 ? (idx ^ rsw) : idx));
      }
      #pragma unroll
      for (int i = 0; i < 4; ++i) {
        int idx = (wn + i * 16 + frow) * BK + ks * 32 + fk;
        bF[i] = *(const short8*)(sB + (BK == 64 ? (idx ^ rsw) : idx));
      }
      #pragma unroll
      for (int mi = 0; mi < 4; ++mi)
        #pragma unroll
        for (int ni = 0; ni < 4; ++ni)
          acc[mi][ni] = __builtin_amdgcn_mfma_f32_16x16x32_bf16(aF[mi], bF[ni], acc[mi][ni], 0, 0, 0);
    }
  }
  const int ccol = lane & 15, crow = (lane >> 4) << 2;
  #pragma unroll
  for (int mi = 0; mi < 4; ++mi) {
    #pragma unroll
    for (int ni = 0; ni < 4; ++ni) {
      long gr0 = arow0 + wm + mi * 16 + crow;
      long gc = brow0 + wn + ni * 16 + ccol;
      if (brow0 + wn + ni * 16 >= NLIM) continue;   // unused cols (zero-pad region)
      #pragma unroll
      for (int r = 0; r < 4; ++r) {
        float v = acc[mi][ni][r];
        long idx = (gr0 + r) * (long)ldc + gc;
        if (EPI == 0) {
          C[idx] = v;
        } else if (EPI == 1) {
          Cb[idx] = f2bf(v);
        } else if (EPI == 2) {
          float x = v + bias[gc];
          Cb[idx] = f2bf((x > 20.f) ? x : log1pf(__expf(x)));
        } else {
          __builtin_nontemporal_store(v + bias[gc], &C[idx]);
        }
      }
    }
  }
}

// ---------------- decode GEMM: 256x128 tile, 8 waves, BK=32, 2-phase dbuf ----------------
__global__ __launch_bounds__(512) void gemm_dec(
    const u16* __restrict__ A, const u16* __restrict__ W,
    float* __restrict__ C, const float* __restrict__ bias) {
  const int tid = threadIdx.x;
  const int nwg = gridDim.x * gridDim.y;      // 250*16 = 4000
  const int wgid = blockIdx.y * gridDim.x + blockIdx.x;
  const int q = nwg >> 3;
  const int swz = (wgid & 7) * q + (wgid >> 3);
  const int bn = swz % gridDim.x, bm = swz / gridDim.x;
  const int wave = tid >> 6, lane = tid & 63;
  const int wm = (wave >> 1) << 6;            // 0,64,128,192
  const int wn = (wave & 1) << 6;             // 0,64
  __shared__ __align__(16) u16 sA[2][256 * 32];  // 2 x 16 KB
  __shared__ __align__(16) u16 sB[2][128 * 32];  // 2 x 8 KB
  f32x4 acc[4][4] = {};
  const long arow0 = (long)bm * 256, brow0 = (long)bn * 128;
  const int frow = lane & 15, fk = (lane >> 4) << 3;
  const int srow = lane >> 2;
  const int scol = (((lane & 3) ^ (srow & 3)) << 3);
  #pragma unroll
  for (int i = 0; i < 2; ++i) {
    int c = wave * 2 + i;
    GLOAD16(A + (arow0 + 16 * c + srow) * (long)DMODEL + scol, sA[0] + c * 512);
  }
  GLOAD16(W + (brow0 + 16 * wave + srow) * (long)DMODEL + scol, sB[0] + wave * 512);
  asm volatile("s_waitcnt vmcnt(0)" ::: "memory");
  __syncthreads();
  int cur = 0;
  for (int k0 = 0; k0 < DMODEL; k0 += 32) {
    if (k0 + 32 < DMODEL) {
      int nb = cur ^ 1;
      #pragma unroll
      for (int i = 0; i < 2; ++i) {
        int c = wave * 2 + i;
        GLOAD16(A + (arow0 + 16 * c + srow) * (long)DMODEL + k0 + 32 + scol, sA[nb] + c * 512);
      }
      GLOAD16(W + (brow0 + 16 * wave + srow) * (long)DMODEL + k0 + 32 + scol, sB[nb] + wave * 512);
    }
    short8 aF[4], bF[4];
    #pragma unroll
    for (int i = 0; i < 4; ++i) {
      int row = wm + i * 16 + frow;
      aF[i] = *(const short8*)(sA[cur] + ((row * 32 + fk) ^ ((row & 3) << 3)));
    }
    #pragma unroll
    for (int i = 0; i < 4; ++i) {
      int row = wn + i * 16 + frow;
      bF[i] = *(const short8*)(sB[cur] + ((row * 32 + fk) ^ ((row & 3) << 3)));
    }
    #pragma unroll
    for (int mi = 0; mi < 4; ++mi)
      #pragma unroll
      for (int ni = 0; ni < 4; ++ni)
        acc[mi][ni] = __builtin_amdgcn_mfma_f32_16x16x32_bf16(aF[mi], bF[ni], acc[mi][ni], 0, 0, 0);
    asm volatile("s_waitcnt vmcnt(0)" ::: "memory");
    __syncthreads();
    cur ^= 1;
  }
  const int ccol = lane & 15, crow = (lane >> 4) << 2;
  #pragma unroll
  for (int mi = 0; mi < 4; ++mi) {
    #pragma unroll
    for (int ni = 0; ni < 4; ++ni) {
      long gr0 = arow0 + wm + mi * 16 + crow;
      long gc = brow0 + wn + ni * 16 + ccol;
      float bv = bias[gc];
      #pragma unroll
      for (int r = 0; r < 4; ++r)
        __builtin_nontemporal_store(acc[mi][ni][r] + bv, &C[(gr0 + r) * (long)VOCAB + gc]);
    }
  }
}

// combine split-K partials for x_proj: bf16 cols 0..31 (dt input), f32 cols 32..63 (B/C)
__global__ __launch_bounds__(256) void xp_comb_k(const float* __restrict__ P, float* __restrict__ xd,
                          u16* __restrict__ xdb) {
  long i = (long)blockIdx.x * 256 + threadIdx.x; // MROWS*128
  int col = (int)(i & 127);
  if (col >= 64) return;
  float s = 0.f;
  #pragma unroll
  for (int z = 0; z < XP_SPLITK; ++z) s += P[(long)z * MROWS * 128 + i];
  if (col < 32) xdb[i] = f2bf(s);
  else xd[i] = s;
}

// ---------------- chunked selective scan (3-kernel path, NCHUNK=64) ----------------
__global__ __launch_bounds__(256) void scanA_k(const u16* __restrict__ dtb, const u16* __restrict__ ubf,
                        const float* __restrict__ xd, const float* __restrict__ alog_l,
                        float* __restrict__ P, float* __restrict__ S) {
  int bid = blockIdx.x;   // NB*NCHUNK*4 = 512
  int tid = threadIdx.x;
  int b = bid >> 8;
  int c = (bid >> 2) & (NCHUNK - 1);
  int d = ((bid & 3) << 8) + tid;
  long rbase = (long)(b * SEQ + c * LCHUNK);
  __shared__ __align__(16) float sB[LCHUNK][NSTATE];
  if (tid < 128) {
    int t = tid >> 2, k4 = (tid & 3) << 2;
    *(f32x4*)&sB[t][k4] = *(const f32x4*)(xd + (rbase + t) * 128 + RKK + k4);
  }
  u16 dtv[LCHUNK], uv[LCHUNK];
  const u16* dp = dtb + rbase * DINNER + d;
  const u16* up = ubf + rbase * DINNER + d;
  #pragma unroll
  for (int tt = 0; tt < LCHUNK; ++tt) { dtv[tt] = dp[(long)tt * DINNER]; uv[tt] = up[(long)tt * DINNER]; }
  float A[NSTATE], h[NSTATE];
  #pragma unroll
  for (int n4 = 0; n4 < 4; ++n4) {
    f32x4 a4 = *(const f32x4*)(alog_l + d * NSTATE + n4 * 4);
    #pragma unroll
    for (int j = 0; j < 4; ++j) { A[n4 * 4 + j] = -__expf(a4[j]); h[n4 * 4 + j] = 0.f; }
  }
  __syncthreads();
  float dsum = 0.f;
  #pragma unroll
  for (int tt = 0; tt < LCHUNK; ++tt) {
    float dv = bf2f(dtv[tt]);
    float du = dv * bf2f(uv[tt]);
    dsum += dv;
    f32x4 b0 = *(const f32x4*)&sB[tt][0], b1 = *(const f32x4*)&sB[tt][4];
    f32x4 b2 = *(const f32x4*)&sB[tt][8], b3 = *(const f32x4*)&sB[tt][12];
    #pragma unroll
    for (int n = 0; n < NSTATE; ++n) {
      float dA = __expf(dv * A[n]);
      float bx = (n < 4) ? b0[n & 3] : (n < 8) ? b1[n & 3] : (n < 12) ? b2[n & 3] : b3[n & 3];
      h[n] = dA * h[n] + du * bx;
    }
  }
  long base = (((long)(b * DINNER + d)) * NCHUNK + c) * NSTATE;
  #pragma unroll
  for (int n4 = 0; n4 < 4; ++n4) {
    f32x4 pv, sv;
    #pragma unroll
    for (int j = 0; j < 4; ++j) { pv[j] = __expf(A[n4 * 4 + j] * dsum); sv[j] = h[n4 * 4 + j]; }
    *(f32x4*)(P + base + n4 * 4) = pv;
    *(f32x4*)(S + base + n4 * 4) = sv;
  }
}

// phase B: wave-parallel Kogge-Stone scan over chunks. wave = one (b,d); lane = chunk.
__global__ __launch_bounds__(256) void scanB_k(const float* __restrict__ P, const float* __restrict__ S,
                        float* __restrict__ Hin) {
  int w = blockIdx.x * 4 + (threadIdx.x >> 6);  // (b*DINNER + d), 2048 waves
  int lane = threadIdx.x & 63;
  long base = ((long)w * NCHUNK + lane) * NSTATE;
  float p[NSTATE], s[NSTATE];
  #pragma unroll
  for (int n = 0; n < NSTATE; ++n) { p[n] = P[base + n]; s[n] = S[base + n]; }
  #pragma unroll
  for (int off = 1; off < 64; off <<= 1) {
    float pp[NSTATE], sp[NSTATE];
    #pragma unroll
    for (int n = 0; n < NSTATE; ++n) {
      pp[n] = __shfl_up(p[n], off, 64);
      sp[n] = __shfl_up(s[n], off, 64);
    }
    if (lane >= off) {
      #pragma unroll
      for (int n = 0; n < NSTATE; ++n) { s[n] = p[n] * sp[n] + s[n]; p[n] *= pp[n]; }
    }
  }
  #pragma unroll
  for (int n = 0; n < NSTATE; ++n) {
    float hv = __shfl_up(s[n], 1, 64);
    Hin[base + n] = (lane == 0) ? 0.f : hv;
  }
}

// phase C: recompute within chunk with true h_in; y = (h.C + u*D) * silu(z) -> bf16
__global__ __launch_bounds__(256) void scanC_k(const u16* __restrict__ dtb, const u16* __restrict__ ubf,
                        const float* __restrict__ xd, const float* __restrict__ alog_l,
                        const float* __restrict__ Dp_l, const u16* __restrict__ xzb,
                        const float* __restrict__ Hin, u16* __restrict__ ybf) {
  int bid = blockIdx.x;
  int tid = threadIdx.x;
  int b = bid >> 8;
  int c = (bid >> 2) & (NCHUNK - 1);
  int d = ((bid & 3) << 8) + tid;
  long rbase = (long)(b * SEQ + c * LCHUNK);
  __shared__ __align__(16) float sBC[LCHUNK][2 * NSTATE];
  {
    int t = tid >> 3, k4 = (tid & 7) << 2;
    *(f32x4*)&sBC[t][k4] = *(const f32x4*)(xd + (rbase + t) * 128 + RKK + k4);
  }
  u16 dtv[LCHUNK], uv[LCHUNK], zv[LCHUNK];
  const u16* dp = dtb + rbase * DINNER + d;
  const u16* up = ubf + rbase * DINNER + d;
  const u16* zp = xzb + rbase * (2 * DINNER) + DINNER + d;
  #pragma unroll
  for (int tt = 0; tt < LCHUNK; ++tt) {
    dtv[tt] = dp[(long)tt * DINNER]; uv[tt] = up[(long)tt * DINNER];
    zv[tt] = zp[(long)tt * 2 * DINNER];
  }
  float A[NSTATE], h[NSTATE];
  long hbase = (((long)(b * DINNER + d)) * NCHUNK + c) * NSTATE;
  #pragma unroll
  for (int n4 = 0; n4 < 4; ++n4) {
    f32x4 a4 = *(const f32x4*)(alog_l + d * NSTATE + n4 * 4);
    f32x4 h4 = *(const f32x4*)(Hin + hbase + n4 * 4);
    #pragma unroll
    for (int j = 0; j < 4; ++j) { A[n4 * 4 + j] = -__expf(a4[j]); h[n4 * 4 + j] = h4[j]; }
  }
  float Dv = Dp_l[d];
  u16* yp = ybf + rbase * DINNER + d;
  __syncthreads();
  #pragma unroll
  for (int tt = 0; tt < LCHUNK; ++tt) {
    float dv = bf2f(dtv[tt]);
    float uvf = bf2f(uv[tt]);
    float du = dv * uvf;
    f32x4 b0 = *(const f32x4*)&sBC[tt][0], b1 = *(const f32x4*)&sBC[tt][4];
    f32x4 b2 = *(const f32x4*)&sBC[tt][8], b3 = *(const f32x4*)&sBC[tt][12];
    f32x4 c0 = *(const f32x4*)&sBC[tt][16], c1 = *(const f32x4*)&sBC[tt][20];
    f32x4 c2 = *(const f32x4*)&sBC[tt][24], c3 = *(const f32x4*)&sBC[tt][28];
    float y = 0.f;
    #pragma unroll
    for (int n = 0; n < NSTATE; ++n) {
      float dA = __expf(dv * A[n]);
      float bx = (n < 4) ? b0[n & 3] : (n < 8) ? b1[n & 3] : (n < 12) ? b2[n & 3] : b3[n & 3];
      float cx = (n < 4) ? c0[n & 3] : (n < 8) ? c1[n & 3] : (n < 12) ? c2[n & 3] : c3[n & 3];
      h[n] = dA * h[n] + du * bx;
      y += h[n] * cx;
    }
    y += uvf * Dv;
    float z = bf2f(zv[tt]);
    y *= z / (1.f + __expf(-z));
    yp[(long)tt * DINNER] = f2bf(y);
  }
}

// ---------------- launch ----------------
extern "C" void kernel_launch(void* const* d_in, const int* in_sizes, int n_in,
                              void* d_out, int out_size, void* d_ws, size_t ws_size,
                              hipStream_t stream) {
  (void)in_sizes; (void)n_in; (void)out_size; (void)ws_size;
  const int*   ids = (const int*)d_in[0];
  const float* emb = (const float*)d_in[1];
  const float* ipw = (const float*)d_in[2];
  const float* cw  = (const float*)d_in[3];
  const float* cb  = (const float*)d_in[4];
  const float* xpw = (const float*)d_in[5];
  const float* dtw = (const float*)d_in[6];
  const float* dtb = (const float*)d_in[7];
  const float* alg = (const float*)d_in[8];
  const float* Dpp = (const float*)d_in[9];
  const float* opw = (const float*)d_in[10];
  const float* nw  = (const float*)d_in[11];
  const float* nb  = (const float*)d_in[12];
  const float* nfw = (const float*)d_in[13];
  const float* nfb = (const float*)d_in[14];
  const float* dw  = (const float*)d_in[15];
  const float* db  = (const float*)d_in[16];

  char* p = (char*)d_ws;
  auto carve = [&](size_t bytes) { void* r = (void*)p; p += (bytes + 255) & ~(size_t)255; return r; };
  float* resid  = (float*)carve((size_t)MROWS * DMODEL * 4);
  u16*   hmixPb = (u16*)  carve((size_t)OUT_SPLITK * MROWS * DMODEL * 2);
  u16*   hnbf   = (u16*)  carve((size_t)MROWS * DMODEL * 2);
  u16*   hfbf   = (u16*)  carve((size_t)MROWS * DMODEL * 2);
  u16*   xzb    = (u16*)  carve((size_t)MROWS * 2 * DINNER * 2);
  u16*   ubf    = (u16*)  carve((size_t)MROWS * DINNER * 2);
  float* xdbl   = (float*)carve((size_t)MROWS * 128 * 4);
  u16*   xdblbf = (u16*)  carve((size_t)MROWS * 128 * 2);
  float* xdP    = (float*)carve((size_t)XP_SPLITK * MROWS * 128 * 4);
  u16*   dtb16  = (u16*)  carve((size_t)MROWS * DINNER * 2);
  u16*   ybf    = (u16*)  carve((size_t)MROWS * DINNER * 2);
  float* chkP   = (float*)carve((size_t)NB * DINNER * NCHUNK * NSTATE * 4);
  float* chkS   = (float*)carve((size_t)NB * DINNER * NCHUNK * NSTATE * 4);
  float* hin    = (float*)carve((size_t)NB * DINNER * NCHUNK * NSTATE * 4);
  u16*   w_in   = (u16*)carve((size_t)NLAYER * 2 * DINNER * DMODEL * 2);
  u16*   w_xp   = (u16*)carve((size_t)NLAYER * 128 * DINNER * 2);
  u16*   w_dt   = (u16*)carve((size_t)NLAYER * DINNER * RKK * 2);
  u16*   w_out  = (u16*)carve((size_t)NLAYER * DMODEL * DINNER * 2);
  u16*   w_dec  = (u16*)carve((size_t)VOCAB * DMODEL * 2);

  { // weight conversions: single fused kernel (incl. padded xproj)
    long nv = ((long)NLAYER * 2 * DINNER * DMODEL + (long)NLAYER * DINNER * RKK +
               (long)NLAYER * DMODEL * DINNER + (long)VOCAB * DMODEL +
               (long)NLAYER * 128 * DINNER) / 4;
    cvt_all_k<<<(int)((nv + 255) / 256), 256, 0, stream>>>(
        ipw, dtw, opw, dw, xpw, w_in, w_dt, w_out, w_dec, w_xp);
  }

  for (int i = 0; i < NLAYER; ++i) {
    if (i == 0)
      ln_k<0><<<MROWS, 256, 0, stream>>>(ids, emb, resid, nullptr, 0, nw, nb, hnbf);
    else
      ln_k<1><<<MROWS, 256, 0, stream>>>(nullptr, nullptr, resid, hmixPb, (long)MROWS * DMODEL,
                                         nw + i * DMODEL, nb + i * DMODEL, hnbf);
    // xz = hn @ in_proj^T   [4096,2048] bf16
    gemm_bf16<1, 64, false><<<dim3(2 * DINNER / 128, MROWS / 128), 256, 0, stream>>>(
        hnbf, DMODEL, w_in + (long)i * 2 * DINNER * DMODEL, DMODEL,
        nullptr, xzb, 2 * DINNER, nullptr, DMODEL, 0, 0);
    conv_silu_k<<<(MROWS / 8 * DINNER) / 256, 256, 0, stream>>>(
        xzb, cw + (long)i * DINNER * 4, cb + i * DINNER, ubf);
    // xdbl = u @ x_proj^T (padded to 128 cols), split-K=8, write cols<64 only
    gemm_bf16<0, 64, true, 64><<<dim3(1, MROWS / 128, XP_SPLITK), 256, 0, stream>>>(
        ubf, DINNER, w_xp + (long)i * 128 * DINNER, DINNER,
        xdP, nullptr, 128, nullptr, DINNER, XP_KCH, (long)MROWS * 128);
    xp_comb_k<<<(MROWS * 128) / 256, 256, 0, stream>>>(xdP, xdbl, xdblbf);
    // dt = softplus(xdbl[:, :32] @ dt_proj^T + b) -> bf16
    gemm_bf16<2, 32, false><<<dim3(DINNER / 128, MROWS / 128), 256, 0, stream>>>(
        xdblbf, 128, w_dt + (long)i * DINNER * RKK, RKK,
        nullptr, dtb16, DINNER, dtb + i * DINNER, RKK, 0, 0);
    scanA_k<<<NB * NCHUNK * 4, 256, 0, stream>>>(
        dtb16, ubf, xdbl, alg + (long)i * DINNER * NSTATE, chkP, chkS);
    scanB_k<<<(NB * DINNER) / 4, 256, 0, stream>>>(chkP, chkS, hin);
    scanC_k<<<NB * NCHUNK * 4, 256, 0, stream>>>(
        dtb16, ubf, xdbl, alg + (long)i * DINNER * NSTATE, Dpp + i * DINNER, xzb, hin, ybf);
    // hmix = y @ out_proj^T  [4096,512], split-K=4, bf16 partials (summed in next LN)
    gemm_bf16<1, 64, true><<<dim3(DMODEL / 128, MROWS / 128, OUT_SPLITK), 256, 0, stream>>>(
        ybf, DINNER, w_out + (long)i * DMODEL * DINNER, DINNER,
        nullptr, hmixPb, DMODEL, nullptr, DINNER, DINNER / OUT_SPLITK, (long)MROWS * DMODEL);
  }
  ln_k<2><<<MROWS, 256, 0, stream>>>(nullptr, nullptr, resid, hmixPb, (long)MROWS * DMODEL,
                                     nfw, nfb, hfbf);
  // logits = hf @ dec_w^T + dec_b  -> f32 out (256x128 tile, 8 waves, 2-phase, NT)
  gemm_dec<<<dim3(VOCAB / 128, MROWS / 256), 512, 0, stream>>>(
      hfbf, w_dec, (float*)d_out, db);
}